// Round 12
// baseline (276.588 us; speedup 1.0000x reference)
//
#include <hip/hip_runtime.h>
#include <hip/hip_bf16.h>
#include <cstdint>
#include <cstddef>

#define NI 8192
#define NC 8192
#define RV 7
#define DD 256

typedef __bf16  bf16x8 __attribute__((ext_vector_type(8)));
typedef float   f32x4  __attribute__((ext_vector_type(4)));
typedef __fp16  f16x2  __attribute__((ext_vector_type(2)));

// ws layout:
//   imgs: per img-block ib (64, 128 imgs each) x chunk t=r*8+j (56):
//         [4 u][128 row] x 16B = 8KB
//   caps: per cap-block cb (64): [8 j][4 u][128 row] x 16B = 64KB
#define IMGS_WS_BYTES (64u * 56u * 8192u)    /* 29,360,128 */
#define CAPS_WS_OFF   IMGS_WS_BYTES
#define CAPS_WS_BYTES (64u * 65536u)         /* 4,194,304 */
#define WS_NEEDED     ((size_t)(IMGS_WS_BYTES + CAPS_WS_BYTES))

static __device__ __forceinline__ unsigned pkbf(float x, float y) {
  unsigned a = __float_as_uint(x) + 0x8000u;
  unsigned b = __float_as_uint(y) + 0x8000u;
  return __builtin_amdgcn_perm(b, a, 0x07060302u);
}

static __device__ __forceinline__ void gload16(const void* g, void* l) {
  __builtin_amdgcn_global_load_lds(
      (const __attribute__((address_space(1))) void*)g,
      (__attribute__((address_space(3))) void*)l, 16, 0, 0);
}

// ---------------- conversion pre-passes (f32 -> bf16, tile-image layout) ---
__global__ __launch_bounds__(256)
void conv_imgs(const float* __restrict__ imgs, uint4* __restrict__ ws) {
  unsigned T = blockIdx.x * 256u + threadIdx.x;   // 0..1,835,007
  unsigned img = T / 224u;                        // 8192 imgs x 224 units
  unsigned rem = T - img * 224u;
  unsigned r  = rem >> 5;                         // view 0..6
  unsigned ju = rem & 31u;                        // k-unit 0..31 (k = ju*8)
  const float* s = imgs + ((size_t)img * RV + r) * DD + ju * 8u;
  float4 a = *(const float4*)s;
  float4 b = *(const float4*)(s + 4);
  uint4 v = { pkbf(a.x, a.y), pkbf(a.z, a.w), pkbf(b.x, b.y), pkbf(b.z, b.w) };
  unsigned ib = img >> 7, lrow = img & 127u;      // 64 panels x 128 imgs
  unsigned j = ju >> 2, u = ju & 3u;
  unsigned t = r * 8u + j;
  unsigned byteoff = (ib * 56u + t) * 8192u + u * 2048u + lrow * 16u;
  ws[byteoff >> 4] = v;
}

__global__ __launch_bounds__(256)
void conv_caps(const float* __restrict__ caps, uint4* __restrict__ ws) {
  unsigned T = blockIdx.x * 256u + threadIdx.x;   // 0..262,143
  unsigned gr = T >> 5;                           // cap row 0..8191
  unsigned ju = T & 31u;                          // k-unit 0..31
  const float* s = caps + (size_t)gr * DD + ju * 8u;
  float4 a = *(const float4*)s;
  float4 b = *(const float4*)(s + 4);
  uint4 v = { pkbf(a.x, a.y), pkbf(a.z, a.w), pkbf(b.x, b.y), pkbf(b.z, b.w) };
  unsigned cb = gr >> 7, row = gr & 127u;         // 64 panels x 128 rows
  unsigned j = ju >> 2, u = ju & 3u;
  unsigned byteoff = cb * 65536u + j * 8192u + u * 2048u + row * 16u;
  ws[byteoff >> 4] = v;
}

// ---------------- main GEMM+max kernel ------------------------------------
// block tile 128 imgs x 128 caps; 4 waves (2m x 2n), wave tile 64x64.
// LDS = B resident 64KB + A double-buffer 2x8KB = 80KB  -> 2 blocks/CU,
// each with an INDEPENDENT barrier domain: one block's vmcnt drain / JIT
// ds_read latency hides under the other block's MFMA cluster (m114).
// Per-chunk (conservative, provably-correct publication):
//   A-frags JIT read + B-frags(t+1) prefetch -> [auto lgkm] ->
//   stage(t+1) into other A buffer -> 16 MFMA -> vmcnt(0) -> barrier
#define BLOAD(P, JN)                                            \
  P##0 = *(const bf16x8*)(bF + (JN)*8192 + 0*256);              \
  P##1 = *(const bf16x8*)(bF + (JN)*8192 + 1*256);              \
  P##2 = *(const bf16x8*)(bF + (JN)*8192 + 2*256);              \
  P##3 = *(const bf16x8*)(bF + (JN)*8192 + 3*256);

#define CHUNK(BP, BN, PBUF, JNXT, MORE)                                  \
  {                                                                      \
    bf16x8 a0 = *(const bf16x8*)(aF + (PBUF)*8192 + 0*256);              \
    bf16x8 a1 = *(const bf16x8*)(aF + (PBUF)*8192 + 1*256);              \
    bf16x8 a2 = *(const bf16x8*)(aF + (PBUF)*8192 + 2*256);              \
    bf16x8 a3 = *(const bf16x8*)(aF + (PBUF)*8192 + 3*256);              \
    BLOAD(BN, JNXT)                                                      \
    if (MORE) {                                                          \
      gload16(stp,        ldsA + ((PBUF)^1)*8192 + wid*1024);            \
      gload16(stp + 4096, ldsA + ((PBUF)^1)*8192 + 4096 + wid*1024);     \
      stp += 8192;                                                       \
    }                                                                    \
    __builtin_amdgcn_s_setprio(1);                                       \
    acc[0][0] = __builtin_amdgcn_mfma_f32_16x16x32_bf16(a0, BP##0, acc[0][0], 0, 0, 0); \
    acc[1][0] = __builtin_amdgcn_mfma_f32_16x16x32_bf16(a1, BP##0, acc[1][0], 0, 0, 0); \
    acc[2][0] = __builtin_amdgcn_mfma_f32_16x16x32_bf16(a2, BP##0, acc[2][0], 0, 0, 0); \
    acc[3][0] = __builtin_amdgcn_mfma_f32_16x16x32_bf16(a3, BP##0, acc[3][0], 0, 0, 0); \
    acc[0][1] = __builtin_amdgcn_mfma_f32_16x16x32_bf16(a0, BP##1, acc[0][1], 0, 0, 0); \
    acc[1][1] = __builtin_amdgcn_mfma_f32_16x16x32_bf16(a1, BP##1, acc[1][1], 0, 0, 0); \
    acc[2][1] = __builtin_amdgcn_mfma_f32_16x16x32_bf16(a2, BP##1, acc[2][1], 0, 0, 0); \
    acc[3][1] = __builtin_amdgcn_mfma_f32_16x16x32_bf16(a3, BP##1, acc[3][1], 0, 0, 0); \
    acc[0][2] = __builtin_amdgcn_mfma_f32_16x16x32_bf16(a0, BP##2, acc[0][2], 0, 0, 0); \
    acc[1][2] = __builtin_amdgcn_mfma_f32_16x16x32_bf16(a1, BP##2, acc[1][2], 0, 0, 0); \
    acc[2][2] = __builtin_amdgcn_mfma_f32_16x16x32_bf16(a2, BP##2, acc[2][2], 0, 0, 0); \
    acc[3][2] = __builtin_amdgcn_mfma_f32_16x16x32_bf16(a3, BP##2, acc[3][2], 0, 0, 0); \
    acc[0][3] = __builtin_amdgcn_mfma_f32_16x16x32_bf16(a0, BP##3, acc[0][3], 0, 0, 0); \
    acc[1][3] = __builtin_amdgcn_mfma_f32_16x16x32_bf16(a1, BP##3, acc[1][3], 0, 0, 0); \
    acc[2][3] = __builtin_amdgcn_mfma_f32_16x16x32_bf16(a2, BP##3, acc[2][3], 0, 0, 0); \
    acc[3][3] = __builtin_amdgcn_mfma_f32_16x16x32_bf16(a3, BP##3, acc[3][3], 0, 0, 0); \
    __builtin_amdgcn_s_setprio(0);                                       \
    if (MORE) {                                                          \
      asm volatile("s_waitcnt vmcnt(0)" ::: "memory");                   \
      __builtin_amdgcn_s_barrier();                                      \
      asm volatile("" ::: "memory");                                     \
    }                                                                    \
  }

__global__ __launch_bounds__(256, 2)
void mvm_mfma(const char* __restrict__ wi, const char* __restrict__ wcap,
              float* __restrict__ out)
{
  __shared__ __align__(1024) char lds[81920];
  char* const ldsB = lds;            // 64KB caps (full K, [8 j][4 u][128 row])
  char* const ldsA = lds + 65536;    // 2 x 8KB imgs chunk buffers

  const int tid  = threadIdx.x;
  const int lane = tid & 63;
  const int wid  = tid >> 6;   // 0..3
  const int wm   = wid >> 1;   // 0..1 : m-strip of 64
  const int wn   = wid & 1;    // 0..1 : n-strip of 64

  const int bid = (int)blockIdx.x;                 // 4096 blocks
  const int swz = (bid & 7) * 512 + (bid >> 3);    // bijective XCD swizzle
  const int ib  = swz >> 6;    // 0..63 : 64 consecutive swz share one A panel
  const int cb  = swz & 63;    // 0..63

  const char* abase = wi   + (size_t)ib * (56u * 8192u);
  const char* bbase = wcap + (size_t)cb * 65536u;

  // prologue: B (16 gloads of 4KB) + A chunk 0 (2 gloads)
  #pragma unroll
  for (int l = 0; l < 16; ++l)
    gload16(bbase + l * 4096 + tid * 16, ldsB + l * 4096 + wid * 1024);
  gload16(abase + tid * 16,        ldsA + wid * 1024);
  gload16(abase + 4096 + tid * 16, ldsA + 4096 + wid * 1024);
  asm volatile("s_waitcnt vmcnt(0)" ::: "memory");
  __builtin_amdgcn_s_barrier();
  asm volatile("" ::: "memory");

  const int lrow = lane & 15;
  const int lu   = lane >> 4;
  const char* const aF = ldsA + lu * 2048 + (wm * 64 + lrow) * 16;
  const char* const bF = ldsB + lu * 2048 + (wn * 64 + lrow) * 16;
  const char* stp = abase + 8192 + tid * 16;   // next chunk to stage = 1

  bf16x8 bc0, bc1, bc2, bc3, bn0, bn1, bn2, bn3;
  BLOAD(bc, 0)   // B frags for j=0

  f16x2 om[4][4][2];
  #pragma unroll
  for (int m = 0; m < 4; ++m)
    #pragma unroll
    for (int n = 0; n < 4; ++n)
      #pragma unroll
      for (int h = 0; h < 2; ++h)
        om[m][n][h] = (f16x2){(__fp16)-65504.f, (__fp16)-65504.f};

  f32x4 acc[4][4];

  #pragma unroll 1
  for (int r = 0; r < RV; ++r) {
    const bool lastr = (r == RV - 1);
    #pragma unroll
    for (int m = 0; m < 4; ++m)
      #pragma unroll
      for (int n = 0; n < 4; ++n)
        acc[m][n] = (f32x4){0.f, 0.f, 0.f, 0.f};

    // 8 chunks; B frags ping-pong (prefetch j+1 during j); A JIT per chunk.
    CHUNK(bc, bn, 0, 1, true)            // j=0
    CHUNK(bn, bc, 1, 2, true)            // j=1
    CHUNK(bc, bn, 0, 3, true)            // j=2
    CHUNK(bn, bc, 1, 4, true)            // j=3
    CHUNK(bc, bn, 0, 5, true)            // j=4
    CHUNK(bn, bc, 1, 6, true)            // j=5
    CHUNK(bc, bn, 0, 7, true)            // j=6
    CHUNK(bn, bc, 1, 0, !lastr)          // j=7 (prefetch j=0 of next view)

    #pragma unroll
    for (int m = 0; m < 4; ++m)
      #pragma unroll
      for (int n = 0; n < 4; ++n) {
        f16x2 lo = __builtin_amdgcn_cvt_pkrtz(acc[m][n][0], acc[m][n][1]);
        f16x2 hi = __builtin_amdgcn_cvt_pkrtz(acc[m][n][2], acc[m][n][3]);
        om[m][n][0] = __builtin_elementwise_max(om[m][n][0], lo);
        om[m][n][1] = __builtin_elementwise_max(om[m][n][1], hi);
      }
  }

  // epilogue: unpack f16 -> f32 and store
  const int rbase = ib * 128 + wm * 64;
  const int cbase = cb * 128 + wn * 64;
  #pragma unroll
  for (int m = 0; m < 4; ++m)
    #pragma unroll
    for (int h = 0; h < 2; ++h)
      #pragma unroll
      for (int e = 0; e < 2; ++e) {
        size_t ro = (size_t)(rbase + m * 16 + lu * 4 + h * 2 + e) * NC + cbase + lrow;
        #pragma unroll
        for (int n = 0; n < 4; ++n)
          out[ro + n * 16] = (float)om[m][n][h][e];
      }
}

// ---------------- fallback (no-ws path) ------------------------------------
__global__ __launch_bounds__(512, 1)
void mvm_fallback(const float* __restrict__ imgs, const float* __restrict__ caps,
                  float* __restrict__ out)
{
  __shared__ __align__(16) char ldsB[128 * 512];
  __shared__ __align__(16) char ldsA[2][256 * 128];

  const int tid  = threadIdx.x;
  const int lane = tid & 63;
  const int wid  = tid >> 6;
  const int wr   = wid >> 1;
  const int wc   = wid & 1;
  const int i0   = blockIdx.y * 256;
  const int c0   = blockIdx.x * 128;

  #pragma unroll
  for (int it = 0; it < 8; ++it) {
    int c    = tid + it * 512;
    int row  = c >> 5;
    int colb = (c & 31) * 16;
    const float* p = caps + (size_t)(c0 + row) * DD + (c & 31) * 8;
    float4 a = *(const float4*)p;
    float4 b = *(const float4*)(p + 4);
    uint4 v;
    v.x = pkbf(a.x, a.y); v.y = pkbf(a.z, a.w);
    v.z = pkbf(b.x, b.y); v.w = pkbf(b.z, b.w);
    *(uint4*)(ldsB + row * 512 + (colb ^ ((row & 7) << 4))) = v;
  }
  #pragma unroll
  for (int it = 0; it < 4; ++it) {
    int c    = tid + it * 512;
    int row  = c >> 3;
    int colb = (c & 7) * 16;
    const float* p = imgs + ((size_t)(i0 + row) * RV + 0) * DD + (c & 7) * 8;
    float4 a = *(const float4*)p;
    float4 b = *(const float4*)(p + 4);
    uint4 v;
    v.x = pkbf(a.x, a.y); v.y = pkbf(a.z, a.w);
    v.z = pkbf(b.x, b.y); v.w = pkbf(b.z, b.w);
    *(uint4*)(ldsA[0] + row * 128 + (colb ^ ((row & 7) << 4))) = v;
  }
  __syncthreads();

  f32x4 omax[4][4];
  #pragma unroll
  for (int m = 0; m < 4; ++m)
    #pragma unroll
    for (int n = 0; n < 4; ++n)
      #pragma unroll
      for (int j = 0; j < 4; ++j)
        omax[m][n][j] = -3.4e38f;

  f32x4 acc[4][4];
  int cur = 0;
  const int lrow = lane & 15;
  const int lkb  = (lane >> 4) * 16;

  for (int ch = 0; ch < RV * 4; ++ch) {
    const int kc = ch & 3;
    if (kc == 0) {
      #pragma unroll
      for (int m = 0; m < 4; ++m)
        #pragma unroll
        for (int n = 0; n < 4; ++n)
          acc[m][n] = (f32x4){0.f, 0.f, 0.f, 0.f};
    }
    const int  chn  = ch + 1;
    const bool hasn = (chn < RV * 4);
    float4 pf[8];
    if (hasn) {
      const int rn = chn >> 2;
      const int kn = (chn & 3) * 64;
      #pragma unroll
      for (int it = 0; it < 4; ++it) {
        int c   = tid + it * 512;
        int row = c >> 3;
        const float* p = imgs + ((size_t)(i0 + row) * RV + rn) * DD + kn + (c & 7) * 8;
        pf[2 * it]     = *(const float4*)p;
        pf[2 * it + 1] = *(const float4*)(p + 4);
      }
    }
    #pragma unroll
    for (int ks = 0; ks < 2; ++ks) {
      bf16x8 af[4], bfr[4];
      #pragma unroll
      for (int m = 0; m < 4; ++m) {
        int row = wr * 64 + m * 16 + lrow;
        af[m] = *(const bf16x8*)(ldsA[cur] + row * 128 + ((ks * 64 + lkb) ^ ((row & 7) << 4)));
      }
      #pragma unroll
      for (int n = 0; n < 4; ++n) {
        int row = wc * 64 + n * 16 + lrow;
        bfr[n] = *(const bf16x8*)(ldsB + row * 512 + (((ch & 3) * 128 + ks * 64 + lkb) ^ ((row & 7) << 4)));
      }
      #pragma unroll
      for (int m = 0; m < 4; ++m)
        #pragma unroll
        for (int n = 0; n < 4; ++n)
          acc[m][n] = __builtin_amdgcn_mfma_f32_16x16x32_bf16(af[m], bfr[n], acc[m][n], 0, 0, 0);
    }
    if (hasn) {
      #pragma unroll
      for (int it = 0; it < 4; ++it) {
        int c    = tid + it * 512;
        int row  = c >> 3;
        int colb = (c & 7) * 16;
        uint4 v;
        v.x = pkbf(pf[2 * it].x,     pf[2 * it].y);
        v.y = pkbf(pf[2 * it].z,     pf[2 * it].w);
        v.z = pkbf(pf[2 * it + 1].x, pf[2 * it + 1].y);
        v.w = pkbf(pf[2 * it + 1].z, pf[2 * it + 1].w);
        *(uint4*)(ldsA[cur ^ 1] + row * 128 + (colb ^ ((row & 7) << 4))) = v;
      }
    }
    __syncthreads();
    cur ^= 1;
    if (kc == 3) {
      #pragma unroll
      for (int m = 0; m < 4; ++m)
        #pragma unroll
        for (int n = 0; n < 4; ++n)
          #pragma unroll
          for (int j = 0; j < 4; ++j)
            omax[m][n][j] = fmaxf(omax[m][n][j], acc[m][n][j]);
    }
  }

  const int rbase = i0 + wr * 64;
  const int cbase = c0 + wc * 64;
  const int lr4   = (lane >> 4) * 4;
  const int lc    = lane & 15;
  #pragma unroll
  for (int m = 0; m < 4; ++m)
    #pragma unroll
    for (int j = 0; j < 4; ++j) {
      size_t ro = (size_t)(rbase + m * 16 + lr4 + j) * NC;
      #pragma unroll
      for (int n = 0; n < 4; ++n)
        out[ro + cbase + n * 16 + lc] = omax[m][n][j];
    }
}

extern "C" void kernel_launch(void* const* d_in, const int* in_sizes, int n_in,
                              void* d_out, int out_size, void* d_ws, size_t ws_size,
                              hipStream_t stream) {
  const float* imgs = (const float*)d_in[0];
  const float* caps = (const float*)d_in[1];
  float* out = (float*)d_out;

  if (ws_size >= WS_NEEDED) {
    char* ws = (char*)d_ws;
    conv_imgs<<<7168, 256, 0, stream>>>(imgs, (uint4*)ws);
    conv_caps<<<1024, 256, 0, stream>>>(caps, (uint4*)(ws + CAPS_WS_OFF));
    mvm_mfma<<<4096, 256, 0, stream>>>((const char*)ws, (const char*)(ws + CAPS_WS_OFF), out);
  } else {
    dim3 grid(NC / 128, NI / 256);
    mvm_fallback<<<grid, 512, 0, stream>>>(imgs, caps, out);
  }
}

// Round 13
// 271.826 us; speedup vs baseline: 1.0175x; 1.0175x over previous
//
#include <hip/hip_runtime.h>
#include <hip/hip_bf16.h>
#include <cstdint>
#include <cstddef>

#define NI 8192
#define NC 8192
#define RV 7
#define DD 256

typedef __bf16  bf16x8 __attribute__((ext_vector_type(8)));
typedef float   f32x4  __attribute__((ext_vector_type(4)));
typedef __fp16  f16x2  __attribute__((ext_vector_type(2)));

// ws layout:
//   imgs: per img-block ib (32, 256 imgs) x chunk t=r*8+j (56):
//         [4 u][256 row] x 16B = 16KB   (exact per-lane A-fragment order)
//   caps: per cap-block cb (64): [8 j][4 u][128 row] x 16B = 64KB
#define IMGS_WS_BYTES (32u * 56u * 16384u)   /* 29,360,128 */
#define CAPS_WS_OFF   IMGS_WS_BYTES
#define CAPS_WS_BYTES (64u * 65536u)         /* 4,194,304 */
#define WS_NEEDED     ((size_t)(IMGS_WS_BYTES + CAPS_WS_BYTES))

static __device__ __forceinline__ unsigned pkbf(float x, float y) {
  unsigned a = __float_as_uint(x) + 0x8000u;
  unsigned b = __float_as_uint(y) + 0x8000u;
  return __builtin_amdgcn_perm(b, a, 0x07060302u);
}

static __device__ __forceinline__ void gload16(const void* g, void* l) {
  __builtin_amdgcn_global_load_lds(
      (const __attribute__((address_space(1))) void*)g,
      (__attribute__((address_space(3))) void*)l, 16, 0, 0);
}

// ---------------- conversion pre-passes (f32 -> bf16, tile-image layout) ---
__global__ __launch_bounds__(256)
void conv_imgs(const float* __restrict__ imgs, uint4* __restrict__ ws) {
  unsigned T = blockIdx.x * 256u + threadIdx.x;   // 0..1,835,007
  unsigned img = T / 224u;                        // 8192 imgs x 224 units
  unsigned rem = T - img * 224u;
  unsigned r  = rem >> 5;                         // view 0..6
  unsigned ju = rem & 31u;                        // k-unit 0..31 (k = ju*8)
  const float* s = imgs + ((size_t)img * RV + r) * DD + ju * 8u;
  float4 a = *(const float4*)s;
  float4 b = *(const float4*)(s + 4);
  uint4 v = { pkbf(a.x, a.y), pkbf(a.z, a.w), pkbf(b.x, b.y), pkbf(b.z, b.w) };
  unsigned ib = img >> 8, lrow = img & 255u;      // 32 panels x 256 imgs
  unsigned j = ju >> 2, u = ju & 3u;
  unsigned t = r * 8u + j;
  unsigned byteoff = (ib * 56u + t) * 16384u + u * 4096u + lrow * 16u;
  ws[byteoff >> 4] = v;
}

__global__ __launch_bounds__(256)
void conv_caps(const float* __restrict__ caps, uint4* __restrict__ ws) {
  unsigned T = blockIdx.x * 256u + threadIdx.x;   // 0..262,143
  unsigned gr = T >> 5;                           // cap row 0..8191
  unsigned ju = T & 31u;                          // k-unit 0..31
  const float* s = caps + (size_t)gr * DD + ju * 8u;
  float4 a = *(const float4*)s;
  float4 b = *(const float4*)(s + 4);
  uint4 v = { pkbf(a.x, a.y), pkbf(a.z, a.w), pkbf(b.x, b.y), pkbf(b.z, b.w) };
  unsigned cb = gr >> 7, row = gr & 127u;         // 64 panels x 128 rows
  unsigned j = ju >> 2, u = ju & 3u;
  unsigned byteoff = cb * 65536u + j * 8192u + u * 2048u + row * 16u;
  ws[byteoff >> 4] = v;
}

// ---------------- main GEMM+max kernel ------------------------------------
// block tile 256 imgs x 128 caps; 8 waves (4m x 2n), wave tile 64x64.
// B resident in LDS (64KB, ONE prologue barrier). A fragments load
// global->VGPR directly (ws is in exact fragment order; panel 917KB is
// L2-resident for the co-XCD block group). Main loop has ZERO barriers and
// ZERO LDS writes: per chunk, prefetch next A (4 global b128) + next B
// (4 ds b128) then run 16 MFMA on current regs. Compiler emits counted
// vmcnt/lgkmcnt with one full chunk (~500 cyc) of slack. Register budget
// (wave 64x64): acc 64 + om 32 + A/B ping-pong 64 + addr ~14 < 256.
#define CHUNK(AC, AN, BC, BN, JNXT)                                      \
  {                                                                      \
    AN##0 = *(const bf16x8*)(ap + 0 * 256);                              \
    AN##1 = *(const bf16x8*)(ap + 1 * 256);                              \
    AN##2 = *(const bf16x8*)(ap + 2 * 256);                              \
    AN##3 = *(const bf16x8*)(ap + 3 * 256);                              \
    BN##0 = *(const bf16x8*)(bF + (JNXT) * 8192 + 0 * 256);              \
    BN##1 = *(const bf16x8*)(bF + (JNXT) * 8192 + 1 * 256);              \
    BN##2 = *(const bf16x8*)(bF + (JNXT) * 8192 + 2 * 256);              \
    BN##3 = *(const bf16x8*)(bF + (JNXT) * 8192 + 3 * 256);              \
    ap += 16384;                                                         \
    __builtin_amdgcn_s_setprio(1);                                       \
    acc[0][0] = __builtin_amdgcn_mfma_f32_16x16x32_bf16(AC##0, BC##0, acc[0][0], 0, 0, 0); \
    acc[1][0] = __builtin_amdgcn_mfma_f32_16x16x32_bf16(AC##1, BC##0, acc[1][0], 0, 0, 0); \
    acc[2][0] = __builtin_amdgcn_mfma_f32_16x16x32_bf16(AC##2, BC##0, acc[2][0], 0, 0, 0); \
    acc[3][0] = __builtin_amdgcn_mfma_f32_16x16x32_bf16(AC##3, BC##0, acc[3][0], 0, 0, 0); \
    acc[0][1] = __builtin_amdgcn_mfma_f32_16x16x32_bf16(AC##0, BC##1, acc[0][1], 0, 0, 0); \
    acc[1][1] = __builtin_amdgcn_mfma_f32_16x16x32_bf16(AC##1, BC##1, acc[1][1], 0, 0, 0); \
    acc[2][1] = __builtin_amdgcn_mfma_f32_16x16x32_bf16(AC##2, BC##1, acc[2][1], 0, 0, 0); \
    acc[3][1] = __builtin_amdgcn_mfma_f32_16x16x32_bf16(AC##3, BC##1, acc[3][1], 0, 0, 0); \
    acc[0][2] = __builtin_amdgcn_mfma_f32_16x16x32_bf16(AC##0, BC##2, acc[0][2], 0, 0, 0); \
    acc[1][2] = __builtin_amdgcn_mfma_f32_16x16x32_bf16(AC##1, BC##2, acc[1][2], 0, 0, 0); \
    acc[2][2] = __builtin_amdgcn_mfma_f32_16x16x32_bf16(AC##2, BC##2, acc[2][2], 0, 0, 0); \
    acc[3][2] = __builtin_amdgcn_mfma_f32_16x16x32_bf16(AC##3, BC##2, acc[3][2], 0, 0, 0); \
    acc[0][3] = __builtin_amdgcn_mfma_f32_16x16x32_bf16(AC##0, BC##3, acc[0][3], 0, 0, 0); \
    acc[1][3] = __builtin_amdgcn_mfma_f32_16x16x32_bf16(AC##1, BC##3, acc[1][3], 0, 0, 0); \
    acc[2][3] = __builtin_amdgcn_mfma_f32_16x16x32_bf16(AC##2, BC##3, acc[2][3], 0, 0, 0); \
    acc[3][3] = __builtin_amdgcn_mfma_f32_16x16x32_bf16(AC##3, BC##3, acc[3][3], 0, 0, 0); \
    __builtin_amdgcn_s_setprio(0);                                       \
  }

__global__ __launch_bounds__(512, 2)
void mvm_mfma(const char* __restrict__ wi, const char* __restrict__ wcap,
              float* __restrict__ out)
{
  __shared__ __align__(1024) char ldsB[65536];   // caps panel, full K

  const int tid  = threadIdx.x;
  const int lane = tid & 63;
  const int wid  = tid >> 6;   // 0..7
  const int wm   = wid >> 1;   // 0..3 : m-strip of 64
  const int wn   = wid & 1;    // 0..1 : n-strip of 64

  const int bid = (int)blockIdx.x;                 // 2048 blocks
  const int swz = (bid & 7) * 256 + (bid >> 3);    // bijective XCD swizzle
  const int ib  = swz >> 6;    // 0..31 : 64 consecutive swz share one A panel
  const int cb  = swz & 63;    // 0..63

  const char* abase = wi   + (size_t)ib * (56u * 16384u);
  const char* bbase = wcap + (size_t)cb * 65536u;

  // prologue: stage B panel to LDS (only barrier in the kernel)
  #pragma unroll
  for (int l = 0; l < 8; ++l)
    gload16(bbase + l * 8192 + tid * 16, ldsB + l * 8192 + wid * 1024);
  asm volatile("s_waitcnt vmcnt(0)" ::: "memory");
  __builtin_amdgcn_s_barrier();
  asm volatile("" ::: "memory");

  const int lrow = lane & 15;
  const int lu   = lane >> 4;
  const char* ap = abase + lu * 4096 + (wm * 64 + lrow) * 16;
  const char* const bF = ldsB + lu * 2048 + (wn * 64 + lrow) * 16;

  bf16x8 Ac0, Ac1, Ac2, Ac3, An0, An1, An2, An3;
  bf16x8 Bc0, Bc1, Bc2, Bc3, Bn0, Bn1, Bn2, Bn3;

  // load chunk 0 fragments
  Ac0 = *(const bf16x8*)(ap + 0 * 256);
  Ac1 = *(const bf16x8*)(ap + 1 * 256);
  Ac2 = *(const bf16x8*)(ap + 2 * 256);
  Ac3 = *(const bf16x8*)(ap + 3 * 256);
  Bc0 = *(const bf16x8*)(bF + 0 * 256);
  Bc1 = *(const bf16x8*)(bF + 1 * 256);
  Bc2 = *(const bf16x8*)(bF + 2 * 256);
  Bc3 = *(const bf16x8*)(bF + 3 * 256);
  ap += 16384;

  f16x2 om[4][4][2];
  #pragma unroll
  for (int m = 0; m < 4; ++m)
    #pragma unroll
    for (int n = 0; n < 4; ++n)
      #pragma unroll
      for (int h = 0; h < 2; ++h)
        om[m][n][h] = (f16x2){(__fp16)-65504.f, (__fp16)-65504.f};

  f32x4 acc[4][4];

  #pragma unroll 1
  for (int r = 0; r < RV; ++r) {
    #pragma unroll
    for (int m = 0; m < 4; ++m)
      #pragma unroll
      for (int n = 0; n < 4; ++n)
        acc[m][n] = (f32x4){0.f, 0.f, 0.f, 0.f};

    // 8 chunks; prefetch A(t+1) global + B(j+1) LDS before MFMA(t).
    CHUNK(Ac, An, Bc, Bn, 1)   // j=0
    CHUNK(An, Ac, Bn, Bc, 2)   // j=1
    CHUNK(Ac, An, Bc, Bn, 3)   // j=2
    CHUNK(An, Ac, Bn, Bc, 4)   // j=3
    CHUNK(Ac, An, Bc, Bn, 5)   // j=4
    CHUNK(An, Ac, Bn, Bc, 6)   // j=5
    CHUNK(Ac, An, Bc, Bn, 7)   // j=6
    CHUNK(An, Ac, Bn, Bc, 0)   // j=7 -> prefetch next view's chunk 0
    // (after the last view the final prefetch reads the caps region of ws:
    //  in-bounds, values never consumed)

    #pragma unroll
    for (int m = 0; m < 4; ++m)
      #pragma unroll
      for (int n = 0; n < 4; ++n) {
        f16x2 lo = __builtin_amdgcn_cvt_pkrtz(acc[m][n][0], acc[m][n][1]);
        f16x2 hi = __builtin_amdgcn_cvt_pkrtz(acc[m][n][2], acc[m][n][3]);
        om[m][n][0] = __builtin_elementwise_max(om[m][n][0], lo);
        om[m][n][1] = __builtin_elementwise_max(om[m][n][1], hi);
      }
  }

  // epilogue: unpack f16 -> f32 and store
  const int rbase = ib * 256 + wm * 64;
  const int cbase = cb * 128 + wn * 64;
  #pragma unroll
  for (int m = 0; m < 4; ++m)
    #pragma unroll
    for (int h = 0; h < 2; ++h)
      #pragma unroll
      for (int e = 0; e < 2; ++e) {
        size_t ro = (size_t)(rbase + m * 16 + lu * 4 + h * 2 + e) * NC + cbase + lrow;
        #pragma unroll
        for (int n = 0; n < 4; ++n)
          out[ro + n * 16] = (float)om[m][n][h][e];
      }
}

// ---------------- fallback (no-ws path) ------------------------------------
__global__ __launch_bounds__(512, 1)
void mvm_fallback(const float* __restrict__ imgs, const float* __restrict__ caps,
                  float* __restrict__ out)
{
  __shared__ __align__(16) char ldsB[128 * 512];
  __shared__ __align__(16) char ldsA[2][256 * 128];

  const int tid  = threadIdx.x;
  const int lane = tid & 63;
  const int wid  = tid >> 6;
  const int wr   = wid >> 1;
  const int wc   = wid & 1;
  const int i0   = blockIdx.y * 256;
  const int c0   = blockIdx.x * 128;

  #pragma unroll
  for (int it = 0; it < 8; ++it) {
    int c    = tid + it * 512;
    int row  = c >> 5;
    int colb = (c & 31) * 16;
    const float* p = caps + (size_t)(c0 + row) * DD + (c & 31) * 8;
    float4 a = *(const float4*)p;
    float4 b = *(const float4*)(p + 4);
    uint4 v;
    v.x = pkbf(a.x, a.y); v.y = pkbf(a.z, a.w);
    v.z = pkbf(b.x, b.y); v.w = pkbf(b.z, b.w);
    *(uint4*)(ldsB + row * 512 + (colb ^ ((row & 7) << 4))) = v;
  }
  #pragma unroll
  for (int it = 0; it < 4; ++it) {
    int c    = tid + it * 512;
    int row  = c >> 3;
    int colb = (c & 7) * 16;
    const float* p = imgs + ((size_t)(i0 + row) * RV + 0) * DD + (c & 7) * 8;
    float4 a = *(const float4*)p;
    float4 b = *(const float4*)(p + 4);
    uint4 v;
    v.x = pkbf(a.x, a.y); v.y = pkbf(a.z, a.w);
    v.z = pkbf(b.x, b.y); v.w = pkbf(b.z, b.w);
    *(uint4*)(ldsA[0] + row * 128 + (colb ^ ((row & 7) << 4))) = v;
  }
  __syncthreads();

  f32x4 omax[4][4];
  #pragma unroll
  for (int m = 0; m < 4; ++m)
    #pragma unroll
    for (int n = 0; n < 4; ++n)
      #pragma unroll
      for (int j = 0; j < 4; ++j)
        omax[m][n][j] = -3.4e38f;

  f32x4 acc[4][4];
  int cur = 0;
  const int lrow = lane & 15;
  const int lkb  = (lane >> 4) * 16;

  for (int ch = 0; ch < RV * 4; ++ch) {
    const int kc = ch & 3;
    if (kc == 0) {
      #pragma unroll
      for (int m = 0; m < 4; ++m)
        #pragma unroll
        for (int n = 0; n < 4; ++n)
          acc[m][n] = (f32x4){0.f, 0.f, 0.f, 0.f};
    }
    const int  chn  = ch + 1;
    const bool hasn = (chn < RV * 4);
    float4 pf[8];
    if (hasn) {
      const int rn = chn >> 2;
      const int kn = (chn & 3) * 64;
      #pragma unroll
      for (int it = 0; it < 4; ++it) {
        int c   = tid + it * 512;
        int row = c >> 3;
        const float* p = imgs + ((size_t)(i0 + row) * RV + rn) * DD + kn + (c & 7) * 8;
        pf[2 * it]     = *(const float4*)p;
        pf[2 * it + 1] = *(const float4*)(p + 4);
      }
    }
    #pragma unroll
    for (int ks = 0; ks < 2; ++ks) {
      bf16x8 af[4], bfr[4];
      #pragma unroll
      for (int m = 0; m < 4; ++m) {
        int row = wr * 64 + m * 16 + lrow;
        af[m] = *(const bf16x8*)(ldsA[cur] + row * 128 + ((ks * 64 + lkb) ^ ((row & 7) << 4)));
      }
      #pragma unroll
      for (int n = 0; n < 4; ++n) {
        int row = wc * 64 + n * 16 + lrow;
        bfr[n] = *(const bf16x8*)(ldsB + row * 512 + (((ch & 3) * 128 + ks * 64 + lkb) ^ ((row & 7) << 4)));
      }
      #pragma unroll
      for (int m = 0; m < 4; ++m)
        #pragma unroll
        for (int n = 0; n < 4; ++n)
          acc[m][n] = __builtin_amdgcn_mfma_f32_16x16x32_bf16(af[m], bfr[n], acc[m][n], 0, 0, 0);
    }
    if (hasn) {
      #pragma unroll
      for (int it = 0; it < 4; ++it) {
        int c    = tid + it * 512;
        int row  = c >> 3;
        int colb = (c & 7) * 16;
        uint4 v;
        v.x = pkbf(pf[2 * it].x,     pf[2 * it].y);
        v.y = pkbf(pf[2 * it].z,     pf[2 * it].w);
        v.z = pkbf(pf[2 * it + 1].x, pf[2 * it + 1].y);
        v.w = pkbf(pf[2 * it + 1].z, pf[2 * it + 1].w);
        *(uint4*)(ldsA[cur ^ 1] + row * 128 + (colb ^ ((row & 7) << 4))) = v;
      }
    }
    __syncthreads();
    cur ^= 1;
    if (kc == 3) {
      #pragma unroll
      for (int m = 0; m < 4; ++m)
        #pragma unroll
        for (int n = 0; n < 4; ++n)
          #pragma unroll
          for (int j = 0; j < 4; ++j)
            omax[m][n][j] = fmaxf(omax[m][n][j], acc[m][n][j]);
    }
  }

  const int rbase = i0 + wr * 64;
  const int cbase = c0 + wc * 64;
  const int lr4   = (lane >> 4) * 4;
  const int lc    = lane & 15;
  #pragma unroll
  for (int m = 0; m < 4; ++m)
    #pragma unroll
    for (int j = 0; j < 4; ++j) {
      size_t ro = (size_t)(rbase + m * 16 + lr4 + j) * NC;
      #pragma unroll
      for (int n = 0; n < 4; ++n)
        out[ro + cbase + n * 16 + lc] = omax[m][n][j];
    }
}

extern "C" void kernel_launch(void* const* d_in, const int* in_sizes, int n_in,
                              void* d_out, int out_size, void* d_ws, size_t ws_size,
                              hipStream_t stream) {
  const float* imgs = (const float*)d_in[0];
  const float* caps = (const float*)d_in[1];
  float* out = (float*)d_out;

  if (ws_size >= WS_NEEDED) {
    char* ws = (char*)d_ws;
    conv_imgs<<<7168, 256, 0, stream>>>(imgs, (uint4*)ws);
    conv_caps<<<1024, 256, 0, stream>>>(caps, (uint4*)(ws + CAPS_WS_OFF));
    mvm_mfma<<<2048, 512, 0, stream>>>((const char*)ws, (const char*)(ws + CAPS_WS_OFF), out);
  } else {
    dim3 grid(NC / 128, NI / 256);
    mvm_fallback<<<grid, 512, 0, stream>>>(imgs, caps, out);
  }
}